// Round 12
// baseline (28.186 us; speedup 1.0000x reference)
//
#include <hip/hip_runtime.h>
#include <hip/hip_bf16.h>

#define NPATCH 196

// ---- setup: ONE block, 256 threads, fully parallel (verified absmax 0.0).
// Computes C[(a*9+q)*4+w] so that feat_w = sum_{a,q} C[(a*9+q)*4+w]*m01[a]*m23[q],
// a = 3*alpha0+alpha1 (wires 0,1), q = 3*alpha2+alpha3 (wires 2,3),
// alpha: 0->1, 1->cos(angle), 2->sin(angle).
__global__ __launch_bounds__(256) void quanv_setup(const float* __restrict__ P,
                                                   float* __restrict__ C) {
  __shared__ float gc[24], gs[24];
  __shared__ float Ur[8][2][2], Ui[8][2][2];  // merged RZ*RY*RX per (d,w)
  __shared__ float Sr[2][16][16], Si[2][16][16];
  __shared__ float A[4][16][16];
  __shared__ float B0[4][3][8][8];
  __shared__ float B1[4][3][3][4][4];
  __shared__ float B2[4][3][3][3][2][2];
  const int tid = threadIdx.x;
  const int row = tid >> 4, col = tid & 15;

  if (tid < 24) {  // P laid out [(d*4+w)*3+g]
    float s, c;
    __sincosf(0.5f * P[tid], &s, &c);
    gc[tid] = c; gs[tid] = s;
  }
  Sr[0][row][col] = (row == col) ? 1.0f : 0.0f;
  Si[0][row][col] = 0.0f;
  __syncthreads();

  if (tid < 8) {  // U = RZ(t3)*RY(t2)*RX(t1), 2x2 complex
    const int base = tid * 3;
    const float c1 = gc[base], s1 = gs[base];
    const float c2 = gc[base + 1], s2 = gs[base + 1];
    const float c3 = gc[base + 2], s3 = gs[base + 2];
    const float m00r = c2 * c1, m00i = s2 * s1;
    const float m01r = -s2 * c1, m01i = -c2 * s1;
    const float m10r = s2 * c1, m10i = -c2 * s1;
    const float m11r = c2 * c1, m11i = -s2 * s1;
    Ur[tid][0][0] = c3 * m00r + s3 * m00i;  Ui[tid][0][0] = c3 * m00i - s3 * m00r;
    Ur[tid][0][1] = c3 * m01r + s3 * m01i;  Ui[tid][0][1] = c3 * m01i - s3 * m01r;
    Ur[tid][1][0] = c3 * m10r - s3 * m10i;  Ui[tid][1][0] = c3 * m10i + s3 * m10r;
    Ur[tid][1][1] = c3 * m11r - s3 * m11i;  Ui[tid][1][1] = c3 * m11i + s3 * m11r;
  }
  __syncthreads();

  int cur = 0;
  for (int d = 0; d < 2; ++d) {
    for (int w = 0; w < 4; ++w) {
      const int gi = d * 4 + w;
      const int m = 8 >> w;
      const int bit = (row & m) ? 1 : 0;
      const int par = row ^ m;
      const int r0 = bit ? par : row, r1 = bit ? row : par;
      const float a_r = Sr[cur][r0][col], a_i = Si[cur][r0][col];
      const float b_r = Sr[cur][r1][col], b_i = Si[cur][r1][col];
      const float u0r = Ur[gi][bit][0], u0i = Ui[gi][bit][0];
      const float u1r = Ur[gi][bit][1], u1i = Ui[gi][bit][1];
      const float rn = u0r * a_r - u0i * a_i + u1r * b_r - u1i * b_i;
      const float in_ = u0r * a_i + u0i * a_r + u1r * b_i + u1i * b_r;
      Sr[cur ^ 1][row][col] = rn;
      Si[cur ^ 1][row][col] = in_;
      cur ^= 1;
      __syncthreads();
    }
    if (d == 0) {  // CNOT ring as one permutation: new[k] = old[chain(k)]
      int k = row;
      k ^= (k & 1) ? 8 : 0;
      k ^= (k & 2) ? 1 : 0;
      k ^= (k & 4) ? 2 : 0;
      k ^= (k & 8) ? 4 : 0;
      const float pr_ = Sr[cur][k][col], pi_ = Si[cur][k][col];
      Sr[cur ^ 1][row][col] = pr_;
      Si[cur ^ 1][row][col] = pi_;
      cur ^= 1;
      __syncthreads();
    }
  }

  {  // A_w[i][j]; second CNOT perm folded into row index
    const int i = row, j = col;
    float s0 = 0, s1 = 0, s2 = 0, s3 = 0;
#pragma unroll
    for (int k = 0; k < 16; ++k) {
      int gk = k;
      gk ^= (gk & 1) ? 8 : 0;
      gk ^= (gk & 2) ? 1 : 0;
      gk ^= (gk & 4) ? 2 : 0;
      gk ^= (gk & 8) ? 4 : 0;
      const float pr = Sr[cur][gk][i] * Sr[cur][gk][j] + Si[cur][gk][i] * Si[cur][gk][j];
      s0 += (k & 8) ? -pr : pr;
      s1 += (k & 4) ? -pr : pr;
      s2 += (k & 2) ? -pr : pr;
      s3 += (k & 1) ? -pr : pr;
    }
    A[0][i][j] = s0; A[1][i][j] = s1; A[2][i][j] = s2; A[3][i][j] = s3;
  }
  __syncthreads();

  // wire-factorized basis transform: a=0: .5(X00+X11); a=1: .5(X00-X11); a=2: .5(X01+X10)
  {  // wire 0
    const int w = tid >> 6, ip = (tid >> 3) & 7, jp = tid & 7;
    const float a00 = A[w][ip][jp],     a11 = A[w][ip + 8][jp + 8];
    const float a01 = A[w][ip][jp + 8], a10 = A[w][ip + 8][jp];
    B0[w][0][ip][jp] = 0.5f * (a00 + a11);
    B0[w][1][ip][jp] = 0.5f * (a00 - a11);
    B0[w][2][ip][jp] = 0.5f * (a01 + a10);
  }
  __syncthreads();
  if (tid < 192) {  // wire 1
    const int w = tid / 48, a0 = (tid / 16) % 3, ii = (tid >> 2) & 3, jj = tid & 3;
    const float a00 = B0[w][a0][ii][jj],     a11 = B0[w][a0][ii + 4][jj + 4];
    const float a01 = B0[w][a0][ii][jj + 4], a10 = B0[w][a0][ii + 4][jj];
    B1[w][a0][0][ii][jj] = 0.5f * (a00 + a11);
    B1[w][a0][1][ii][jj] = 0.5f * (a00 - a11);
    B1[w][a0][2][ii][jj] = 0.5f * (a01 + a10);
  }
  __syncthreads();
  if (tid < 144) {  // wire 2
    const int w = tid / 36, a0 = (tid / 12) % 3, a1 = (tid / 4) % 3;
    const int i3 = (tid >> 1) & 1, j3 = tid & 1;
    const float a00 = B1[w][a0][a1][i3][j3],     a11 = B1[w][a0][a1][i3 + 2][j3 + 2];
    const float a01 = B1[w][a0][a1][i3][j3 + 2], a10 = B1[w][a0][a1][i3 + 2][j3];
    B2[w][a0][a1][0][i3][j3] = 0.5f * (a00 + a11);
    B2[w][a0][a1][1][i3][j3] = 0.5f * (a00 - a11);
    B2[w][a0][a1][2][i3][j3] = 0.5f * (a01 + a10);
  }
  __syncthreads();
  if (tid < 108) {  // wire 3 -> C
    const int w = tid / 27, r = tid % 27;
    const int a0 = r / 9, a1 = (r / 3) % 3, a2 = r % 3;
    const float a00 = B2[w][a0][a1][a2][0][0], a11 = B2[w][a0][a1][a2][1][1];
    const float a01 = B2[w][a0][a1][a2][0][1], a10 = B2[w][a0][a1][a2][1][0];
    const int base = (3 * a0 + a1) * 9 + 3 * a2;
    C[(base + 0) * 4 + w] = 0.5f * (a00 + a11);
    C[(base + 1) * 4 + w] = 0.5f * (a00 - a11);
    C[(base + 2) * 4 + w] = 0.5f * (a01 + a10);
  }
}

// ---- main: TWO images per block. C loads (wave-uniform) and W loads shared
// across both images -> 8 independent FMA chains/thread, ~25% fewer inst/img.
// Reduction: 2-step butterfly -> LDS scatter -> 7x7 two-stage tree (no serial 49).
__global__ __launch_bounds__(256, 4) void quanv_main(const float* __restrict__ x,
                                                     const float* __restrict__ W,
                                                     const float* __restrict__ bias,
                                                     const float* __restrict__ C,
                                                     float* __restrict__ out,
                                                     int B) {
  __shared__ float red2[2][49][10];
  __shared__ float red3[2][10][7];
  __shared__ float logits[2][10];
  const int tid = threadIdx.x;
  const int b0 = blockIdx.x * 2;
  const int b1 = (b0 + 1 < B) ? (b0 + 1) : b0;  // clamp for odd B

  float lgA[10], lgB[10];
#pragma unroll
  for (int k = 0; k < 10; ++k) { lgA[k] = 0.0f; lgB[k] = 0.0f; }

  if (tid < NPATCH) {
    const int pi = tid / 14, pj = tid - pi * 14;
    const int off = pi * 56 + pj * 2;
    const float* pxA = x + b0 * 784 + off;
    const float* pxB = x + b1 * 784 + off;
    const float2 a0 = *reinterpret_cast<const float2*>(pxA);
    const float2 a1 = *reinterpret_cast<const float2*>(pxA + 28);
    const float2 b0v = *reinterpret_cast<const float2*>(pxB);
    const float2 b1v = *reinterpret_cast<const float2*>(pxB + 28);

    float ca0, sa0, ca1, sa1, ca2, sa2, ca3, sa3;
    __sincosf(a0.x, &sa0, &ca0);
    __sincosf(a0.y, &sa1, &ca1);
    __sincosf(a1.x, &sa2, &ca2);
    __sincosf(a1.y, &sa3, &ca3);
    float cb0, sb0, cb1, sb1, cb2, sb2, cb3, sb3;
    __sincosf(b0v.x, &sb0, &cb0);
    __sincosf(b0v.y, &sb1, &cb1);
    __sincosf(b1v.x, &sb2, &cb2);
    __sincosf(b1v.y, &sb3, &cb3);

    const float m01A[9] = {1.0f, ca1, sa1, ca0, ca0 * ca1, ca0 * sa1, sa0, sa0 * ca1, sa0 * sa1};
    const float m23A[9] = {1.0f, ca3, sa3, ca2, ca2 * ca3, ca2 * sa3, sa2, sa2 * ca3, sa2 * sa3};
    const float m01B[9] = {1.0f, cb1, sb1, cb0, cb0 * cb1, cb0 * sb1, sb0, sb0 * cb1, sb0 * sb1};
    const float m23B[9] = {1.0f, cb3, sb3, cb2, cb2 * cb3, cb2 * sb3, sb2, sb2 * cb3, sb2 * sb3};

    float f0A = 0, f1A = 0, f2A = 0, f3A = 0;
    float f0B = 0, f1B = 0, f2B = 0, f3B = 0;
    const float4* C4 = reinterpret_cast<const float4*>(C);
#pragma unroll
    for (int a = 0; a < 9; ++a) {
#pragma unroll
      for (int q = 0; q < 9; ++q) {
        const float4 cc = C4[a * 9 + q];  // wave-uniform, shared by both images
        const float prA = m01A[a] * m23A[q];
        const float prB = m01B[a] * m23B[q];
        f0A += cc.x * prA; f1A += cc.y * prA; f2A += cc.z * prA; f3A += cc.w * prA;
        f0B += cc.x * prB; f1B += cc.y * prB; f2B += cc.z * prB; f3B += cc.w * prB;
      }
    }

    const float* Wp = W + tid * 4;  // feature index = tid*4 + w
#pragma unroll
    for (int k = 0; k < 10; ++k) {
      const float4 wv = *reinterpret_cast<const float4*>(Wp + k * 784);  // shared
      lgA[k] = f0A * wv.x + f1A * wv.y + f2A * wv.z + f3A * wv.w;
      lgB[k] = f0B * wv.x + f1B * wv.y + f2B * wv.z + f3B * wv.w;
    }
  }

  // 2-step butterfly -> 4-lane group sums
#pragma unroll
  for (int k = 0; k < 10; ++k) {
    lgA[k] += __shfl_xor(lgA[k], 1);
    lgA[k] += __shfl_xor(lgA[k], 2);
    lgB[k] += __shfl_xor(lgB[k], 1);
    lgB[k] += __shfl_xor(lgB[k], 2);
  }
  if (tid < NPATCH) {
    const int g = tid >> 2, sub = tid & 3;
#pragma unroll
    for (int k = 0; k < 10; ++k)
      if ((k & 3) == sub) { red2[0][g][k] = lgA[k]; red2[1][g][k] = lgB[k]; }
  }
  __syncthreads();

  // stage 2: 49 groups = 7 x 7 tree
  if (tid < 140) {
    const int img = tid / 70, r = tid - img * 70;
    const int k = r / 7, part = r - k * 7;
    float s = 0.0f;
#pragma unroll
    for (int j = 0; j < 7; ++j) s += red2[img][part * 7 + j][k];
    red3[img][k][part] = s;
  }
  __syncthreads();

  if (tid < 20) {
    const int img = tid / 10, k = tid - img * 10;
    float s = bias[k];
#pragma unroll
    for (int j = 0; j < 7; ++j) s += red3[img][k][j];
    logits[img][k] = s;
  }
  __syncthreads();

  if (tid < 20) {
    const int img = tid / 10, k = tid - img * 10;
    float m = logits[img][0];
#pragma unroll
    for (int kk = 1; kk < 10; ++kk) m = fmaxf(m, logits[img][kk]);
    float se = 0.0f;
#pragma unroll
    for (int kk = 0; kk < 10; ++kk) se += expf(logits[img][kk] - m);
    const float sn = m + logf(se);
    const int b = b0 + img;
    if (b < B) out[b * 10 + k] = logits[img][k] - sn;
  }
}

extern "C" void kernel_launch(void* const* d_in, const int* in_sizes, int n_in,
                              void* d_out, int out_size, void* d_ws, size_t ws_size,
                              hipStream_t stream) {
  const float* x = (const float*)d_in[0];     // (B,1,28,28) f32
  const float* P = (const float*)d_in[1];     // (2,4,3) f32
  const float* W = (const float*)d_in[2];     // (10,784) f32
  const float* bias = (const float*)d_in[3];  // (10,) f32
  float* out = (float*)d_out;                 // (B,10) f32
  float* C = (float*)d_ws;                    // 324 floats scratch
  const int B = out_size / 10;

  quanv_setup<<<1, 256, 0, stream>>>(P, C);
  quanv_main<<<(B + 1) / 2, 256, 0, stream>>>(x, W, bias, C, out, B);
}